// Round 7
// baseline (5022.901 us; speedup 1.0000x reference)
//
#include <hip/hip_runtime.h>

#define Tt 256
#define Bb 32
#define Ff 128
#define Cc 128
#define HA 128
#define LS 1024
#define PR 256
#define SP 128
#define KC 31
#define FLAG_STRIDE 16

typedef __attribute__((ext_vector_type(8))) short bf16x8;
typedef __attribute__((ext_vector_type(4))) short short4v;
typedef __attribute__((ext_vector_type(4))) float f32x4;
typedef unsigned long long u64;

__device__ __forceinline__ unsigned short f2b(float f) {
    unsigned u = __float_as_uint(f);
    unsigned r = (u + 0x7fff + ((u >> 16) & 1)) >> 16;
    return (unsigned short)r;
}
__device__ __forceinline__ float b2f(unsigned short s) {
    return __uint_as_float(((unsigned)s) << 16);
}
__device__ __forceinline__ float sigm(float x) { return __fdividef(1.0f, 1.0f + __expf(-x)); }
__device__ __forceinline__ float ftanh(float x) {
    x = fminf(10.0f, fmaxf(-10.0f, x));
    float t = __expf(2.0f * x);
    return __fdividef(t - 1.0f, t + 1.0f);
}
__device__ __forceinline__ void st_sys_u64(u64* p, u64 v) {
    __hip_atomic_store(p, v, __ATOMIC_RELAXED, __HIP_MEMORY_SCOPE_SYSTEM);
}

// h state layout: [slab][u4=unit>>2][b][4 units] u16; block r sole producer of
// group u4==r (single-producer 64B lines; consumers use plain cached loads on
// cold slab-f addresses).
__device__ __forceinline__ bf16x8 ldh8(const unsigned short* base, int slab, int kb, int b) {
    const u64* p = (const u64*)(base + (size_t)slab * 32768 + (size_t)(kb >> 2) * 128 + b * 4);
    union { bf16x8 v; u64 q[2]; } u;
    u.q[0] = p[0];
    u.q[1] = p[32];
    return u.v;
}

// ---------------------------------------------------------------- repack ----
__global__ __launch_bounds__(256) void k_repack(
    const float* __restrict__ srcA, const float* __restrict__ srcB,
    int kSplit, int K, int total, int interleave, unsigned short* __restrict__ dst)
{
    int t = blockIdx.x * 256 + threadIdx.x;
    if (t >= total) return;
    int l = t & 63, frag = t >> 6;
    int nkc = K >> 5;
    int rt = frag / nkc, kc = frag - rt * nkc;
    int lm = l & 15;
    int g = interleave ? ((lm >> 2) * 1024 + rt * 4 + (lm & 3)) : (rt * 16 + lm);
    int kb = kc * 32 + 8 * (l >> 4);
#pragma unroll
    for (int j = 0; j < 8; ++j) {
        int k = kb + j;
        float f = (k < kSplit) ? srcA[(size_t)g * kSplit + k]
                               : srcB[(size_t)g * (K - kSplit) + (k - kSplit)];
        dst[(size_t)t * 8 + j] = f2b(f);
    }
}

__global__ __launch_bounds__(256) void k_cwp(
    const float* __restrict__ cw, unsigned short* __restrict__ dst)
{
    int t = blockIdx.x * 256 + threadIdx.x;
    if (t >= 512) return;
    int l = t & 63, r = t >> 6;
    int h = r * 16 + (l & 15);
    int kb = 8 * (l >> 4);
#pragma unroll
    for (int j = 0; j < 8; ++j) {
        int k = kb + j;
        dst[(size_t)t * 8 + j] = (k < KC) ? f2b(cw[h * KC + k]) : 0;
    }
}

__global__ __launch_bounds__(256) void k_cvt(
    const float* __restrict__ src, unsigned short* __restrict__ dst, int n)
{
    int i = blockIdx.x * 256 + threadIdx.x;
    if (i < n) dst[i] = f2b(src[i]);
}

__global__ __launch_bounds__(256) void k_fin(
    const float* __restrict__ tf, unsigned short* __restrict__ dst)
{
    int i = blockIdx.x * 256 + threadIdx.x;
    if (i >= Ff * Bb * Cc) return;
    int fb = i >> 7, cpos = i & 127;
    int f = fb >> 5, b = fb & 31;
    float v = (f == 0) ? -9.210340371976182f : tf[((size_t)(f - 1) * Bb + b) * Cc + cpos];
    dst[i] = f2b(v);
}

// ------------------------------------------------- prenet layer (MFMA) -----
__global__ __launch_bounds__(1024) void k_prelayer(
    const unsigned short* __restrict__ Wp, int nkc,
    const unsigned short* __restrict__ X, int rs,
    const float* __restrict__ bias, unsigned short* __restrict__ Y)
{
    int tid = threadIdx.x, l = tid & 63, w = tid >> 6;
    int lm = l & 15, lk = l >> 4;
    int fb0 = blockIdx.x * 16;
    f32x4 acc = {0.f, 0.f, 0.f, 0.f};
    const unsigned short* wp = Wp + (((size_t)w * nkc) << 9) + (l << 3);
    for (int kc = 0; kc < nkc; ++kc) {
        bf16x8 bb = *(const bf16x8*)(X + (size_t)(fb0 + lm) * rs + (kc << 5) + 8 * lk);
        bf16x8 aa = *(const bf16x8*)wp;
        acc = __builtin_amdgcn_mfma_f32_16x16x32_bf16(aa, bb, acc, 0, 0, 0);
        wp += 512;
    }
    short4v o;
#pragma unroll
    for (int rr = 0; rr < 4; ++rr) {
        float v = acc[rr] + bias[w * 16 + 4 * lk + rr];
        o[rr] = (short)f2b(fmaxf(v, 0.f));
    }
    *(short4v*)(Y + (size_t)(fb0 + lm) * 256 + w * 16 + 4 * lk) = o;
}

// ------------------------------------------------- grid barrier ------------
__device__ __forceinline__ int poll_flag(int* p, int it) {
    if ((it & 63) == 63)
        return __hip_atomic_fetch_add(p, 0, __ATOMIC_RELAXED, __HIP_MEMORY_SCOPE_SYSTEM);
    return __hip_atomic_load(p, __ATOMIC_RELAXED, __HIP_MEMORY_SCOPE_SYSTEM);
}
__device__ __forceinline__ void gridbar(int* arr, int* rel, int gen)
{
    __syncthreads();
    if (blockIdx.x == 0) {
        int tid = threadIdx.x;
        if (tid >= 1 && tid < 256) {
            int cnt = 0;
            while (poll_flag(&arr[tid * FLAG_STRIDE], cnt) < gen) {
                __builtin_amdgcn_s_sleep(2);
                if (++cnt > 2000000) break;
            }
        }
        __syncthreads();
        if (tid < 8)
            __hip_atomic_store(&rel[tid * FLAG_STRIDE], gen, __ATOMIC_RELAXED,
                               __HIP_MEMORY_SCOPE_SYSTEM);
    } else {
        if (threadIdx.x == 0) {
            __hip_atomic_store(&arr[blockIdx.x * FLAG_STRIDE], gen, __ATOMIC_RELAXED,
                               __HIP_MEMORY_SCOPE_SYSTEM);
            int cnt = 0;
            while (poll_flag(&rel[(blockIdx.x & 7) * FLAG_STRIDE], cnt) < gen) {
                __builtin_amdgcn_s_sleep(2);
                if (++cnt > 2000000) break;
            }
        }
    }
    __syncthreads();
}

// ------------------------------------------------- branch-free X addressing -
// Address select via ternaries (-> v_cndmask, single basic block) so all
// fragment loads batch into one pipelined IC round trip. o2 = offset of the
// second 8B half; d = byte delta to row lm+16.
__device__ __forceinline__ const char* xaddr1(
    int kk, int f, int lm,
    const unsigned short* p_bf, const unsigned short* ctx_bf,
    const unsigned short* spk_bf, const unsigned short* h1n,
    int& o2, int& d)
{
    const char* ap = (const char*)(p_bf  + (size_t)(f * 32 + lm) * 256 + kk);
    const char* ac = (const char*)(ctx_bf + (size_t)(f * 32 + lm) * 128 + (kk - 256));
    const char* as = (const char*)(spk_bf + (size_t)lm * 128 + (kk - 384));
    const char* ah = (const char*)(h1n + (size_t)f * 32768 + (size_t)((kk - 512) >> 2) * 128 + lm * 4);
    o2 = kk < 512 ? 8 : 256;
    d  = kk < 256 ? 8192 : (kk < 512 ? 4096 : 128);
    return kk < 256 ? ap : (kk < 384 ? ac : (kk < 512 ? as : ah));
}
__device__ __forceinline__ const char* xaddr2(
    int kk, int f, int lm,
    const unsigned short* h1n, const unsigned short* ctx_bf,
    const unsigned short* spk_bf, const unsigned short* h2n,
    int& o2, int& d)
{
    const char* ah1 = (const char*)(h1n + (size_t)f * 32768 + (size_t)(kk >> 2) * 128 + lm * 4);
    const char* ac  = (const char*)(ctx_bf + (size_t)(f * 32 + lm) * 128 + (kk - 1024));
    const char* as  = (const char*)(spk_bf + (size_t)lm * 128 + (kk - 1152));
    const char* ah2 = (const char*)(h2n + (size_t)(f - 1) * 32768 + (size_t)((kk - 1280) >> 2) * 128 + lm * 4);
    o2 = (kk >= 1024 && kk < 1280) ? 8 : 256;
    d  = (kk >= 1024 && kk < 1280) ? 4096 : 128;
    return kk < 1024 ? ah1 : (kk < 1152 ? ac : (kk < 1280 ? as : ah2));
}
union frag_u { u64 q[2]; bf16x8 v; };

// ------------------------------------------------- GEMM2 + cell2 (inline) --
__device__ __forceinline__ void gemm2cell(
    int f, int tid, int l, int w, int lm, int lk, int r,
    const bf16x8 (&w2f)[9],
    const unsigned short* h1n, const unsigned short* ctx_bf,
    const unsigned short* spk_bf, unsigned short* h2n,
    const float* b2l, float* c2_s,
    f32x4 (*red)[2][64], float (*g_s)[4][16][4])
{
    f32x4 a0 = {0.f,0.f,0.f,0.f}, a1 = {0.f,0.f,0.f,0.f};
    // batch 1: slots 0..4
    {
        u64 qa[5][4];
#pragma unroll
        for (int i = 0; i < 5; ++i) {
            int kk = (w * 9 + i) * 32 + 8 * lk;
            int o2, d;
            const char* a = xaddr2(kk, f, lm, h1n, ctx_bf, spk_bf, h2n, o2, d);
            qa[i][0] = *(const u64*)a;       qa[i][1] = *(const u64*)(a + o2);
            qa[i][2] = *(const u64*)(a + d); qa[i][3] = *(const u64*)(a + d + o2);
        }
#pragma unroll
        for (int i = 0; i < 5; ++i) {
            frag_u u0, u1;
            u0.q[0] = qa[i][0]; u0.q[1] = qa[i][1];
            u1.q[0] = qa[i][2]; u1.q[1] = qa[i][3];
            a0 = __builtin_amdgcn_mfma_f32_16x16x32_bf16(w2f[i], u0.v, a0, 0, 0, 0);
            a1 = __builtin_amdgcn_mfma_f32_16x16x32_bf16(w2f[i], u1.v, a1, 0, 0, 0);
        }
    }
    // batch 2: slots 5..8
    {
        u64 qa[4][4];
#pragma unroll
        for (int i = 0; i < 4; ++i) {
            int kk = (w * 9 + 5 + i) * 32 + 8 * lk;
            int o2, d;
            const char* a = xaddr2(kk, f, lm, h1n, ctx_bf, spk_bf, h2n, o2, d);
            qa[i][0] = *(const u64*)a;       qa[i][1] = *(const u64*)(a + o2);
            qa[i][2] = *(const u64*)(a + d); qa[i][3] = *(const u64*)(a + d + o2);
        }
#pragma unroll
        for (int i = 0; i < 4; ++i) {
            frag_u u0, u1;
            u0.q[0] = qa[i][0]; u0.q[1] = qa[i][1];
            u1.q[0] = qa[i][2]; u1.q[1] = qa[i][3];
            a0 = __builtin_amdgcn_mfma_f32_16x16x32_bf16(w2f[5 + i], u0.v, a0, 0, 0, 0);
            a1 = __builtin_amdgcn_mfma_f32_16x16x32_bf16(w2f[5 + i], u1.v, a1, 0, 0, 0);
        }
    }
    __syncthreads();
    red[w][0][l] = a0; red[w][1][l] = a1;
    __syncthreads();
    if (tid < 128) {
        int ct = tid >> 6, ll = tid & 63;
        f32x4 s = red[0][ct][ll];
#pragma unroll
        for (int ww = 1; ww < 8; ++ww) s += red[ww][ct][ll];
        int llm = ll & 15, llk = ll >> 4;
#pragma unroll
        for (int rr = 0; rr < 4; ++rr) g_s[ct][llk][llm][rr] = s[rr];
    }
    __syncthreads();
    if (tid < 32) {
        int b = tid, ct = b >> 4, bl = b & 15;
        u64 pack = 0;
#pragma unroll
        for (int v = 0; v < 4; ++v) {
            int u = r * 4 + v;
            float gi = g_s[ct][0][bl][v] + b2l[u];
            float gf = g_s[ct][1][bl][v] + b2l[1024 + u];
            float gg = g_s[ct][2][bl][v] + b2l[2048 + u];
            float go = g_s[ct][3][bl][v] + b2l[3072 + u];
            float cc = sigm(gf) * c2_s[b + 32 * v] + sigm(gi) * ftanh(gg);
            c2_s[b + 32 * v] = cc;
            pack |= (u64)f2b(sigm(go) * ftanh(cc)) << (16 * v);
        }
        st_sys_u64((u64*)(h2n + (size_t)f * 32768 + (size_t)r * 128 + b * 4), pack);
    }
}

// ------------------------------------------------- persistent decoder ------
__global__ __launch_bounds__(512) void k_persist(
    const unsigned short* __restrict__ W1p, const unsigned short* __restrict__ W2p,
    const unsigned short* __restrict__ p_bf, const unsigned short* __restrict__ spk_bf,
    unsigned short* __restrict__ h1n, unsigned short* __restrict__ h2n,
    unsigned short* __restrict__ ctx_bf,
    const float* __restrict__ b1l, const float* __restrict__ b2l,
    const float* __restrict__ enc, const unsigned short* __restrict__ wqp,
    const float* __restrict__ bq, const unsigned short* __restrict__ cwp,
    const float* __restrict__ cb, const float* __restrict__ av,
    float* __restrict__ align_f, int* __restrict__ bar_arr, int* __restrict__ bar_rel)
{
    const int tid = threadIdx.x;
    const int l = tid & 63, w = tid >> 6;
    const int lm = l & 15, lk = l >> 4;
    const int r = blockIdx.x;

    bf16x8 w1f[6], w2f[9];
#pragma unroll
    for (int i = 0; i < 6; ++i)
        w1f[i] = *(const bf16x8*)(W1p + (((size_t)(r * 48 + w * 6 + i)) << 9) + (l << 3));
#pragma unroll
    for (int i = 0; i < 9; ++i)
        w2f[i] = *(const bf16x8*)(W2p + (((size_t)(r * 72 + w * 9 + i)) << 9) + (l << 3));

    __shared__ f32x4 red[8][2][64];
    __shared__ float g_s[2][4][16][4];
    __shared__ float c1_s[128], c2_s[128];
    __shared__ u64 h1b64[256];           // h1[f+1] row b as bf16 (q B-operand)
    __shared__ float qc_s[128];
    __shared__ float cum_s[292];
    __shared__ float e_s[256], a_s[256];
    __shared__ float ctx_p[4][128];
    __shared__ float redm[16];

    if (tid < 128) { c1_s[tid] = 0.f; c2_s[tid] = 0.f; }
    for (int i = tid; i < 292; i += 512) cum_s[i] = 0.f;
    __syncthreads();

    for (int f = 0; f < 128; ++f) {
        // ---------------- phase 1: GEMM1[f]+cell1, GEMM2[f-1]+cell2 --------
        {
            f32x4 a0 = {0.f,0.f,0.f,0.f}, a1 = {0.f,0.f,0.f,0.f};
            u64 qa[6][4];
#pragma unroll
            for (int i = 0; i < 6; ++i) {
                int kk = (w * 6 + i) * 32 + 8 * lk;
                int o2, d;
                const char* a = xaddr1(kk, f, lm, p_bf, ctx_bf, spk_bf, h1n, o2, d);
                qa[i][0] = *(const u64*)a;       qa[i][1] = *(const u64*)(a + o2);
                qa[i][2] = *(const u64*)(a + d); qa[i][3] = *(const u64*)(a + d + o2);
            }
#pragma unroll
            for (int i = 0; i < 6; ++i) {
                frag_u u0, u1;
                u0.q[0] = qa[i][0]; u0.q[1] = qa[i][1];
                u1.q[0] = qa[i][2]; u1.q[1] = qa[i][3];
                a0 = __builtin_amdgcn_mfma_f32_16x16x32_bf16(w1f[i], u0.v, a0, 0, 0, 0);
                a1 = __builtin_amdgcn_mfma_f32_16x16x32_bf16(w1f[i], u1.v, a1, 0, 0, 0);
            }
            red[w][0][l] = a0; red[w][1][l] = a1;
        }
        __syncthreads();
        if (tid < 128) {
            int ct = tid >> 6, ll = tid & 63;
            f32x4 s = red[0][ct][ll];
#pragma unroll
            for (int ww = 1; ww < 8; ++ww) s += red[ww][ct][ll];
            int llm = ll & 15, llk = ll >> 4;
#pragma unroll
            for (int rr = 0; rr < 4; ++rr) g_s[ct][llk][llm][rr] = s[rr];
        }
        __syncthreads();
        if (tid < 32) {
            int b = tid, ct = b >> 4, bl = b & 15;
            u64 pack = 0;
#pragma unroll
            for (int v = 0; v < 4; ++v) {
                int u = r * 4 + v;
                float gi = g_s[ct][0][bl][v] + b1l[u];
                float gf = g_s[ct][1][bl][v] + b1l[1024 + u];
                float gg = g_s[ct][2][bl][v] + b1l[2048 + u];
                float go = g_s[ct][3][bl][v] + b1l[3072 + u];
                float cc = sigm(gf) * c1_s[b + 32 * v] + sigm(gi) * ftanh(gg);
                c1_s[b + 32 * v] = cc;
                pack |= (u64)f2b(sigm(go) * ftanh(cc)) << (16 * v);
            }
            st_sys_u64((u64*)(h1n + (size_t)(f + 1) * 32768 + (size_t)r * 128 + b * 4), pack);
        }
        if (f >= 1)
            gemm2cell(f, tid, l, w, lm, lk, r, w2f, h1n, ctx_bf, spk_bf, h2n,
                      b2l, c2_s, red, g_s);
        gridbar(bar_arr, bar_rel, 2 * f + 1);

        // ---------------- phase 2: attention (blocks 0..31) ----------------
        if (r < 32) {
            const int b = r;
            if (tid < 256)
                h1b64[tid] = *(const u64*)(h1n + (size_t)(f + 1) * 32768 + (size_t)tid * 128 + b * 4);
            __syncthreads();
            // q = Wq.h1 + bq (+cb folded) via MFMA: wave w = m-tile w; B cols
            // all broadcast h1 -> every col holds q; lanes lm==0 write out.
            {
                const unsigned short* h1b = (const unsigned short*)h1b64;
                f32x4 qacc = {0.f,0.f,0.f,0.f};
#pragma unroll
                for (int kc = 0; kc < 32; ++kc) {
                    bf16x8 hb = *(const bf16x8*)(h1b + kc * 32 + 8 * lk);
                    bf16x8 afr = *(const bf16x8*)(wqp + (((size_t)(w * 32 + kc)) << 9) + (l << 3));
                    qacc = __builtin_amdgcn_mfma_f32_16x16x32_bf16(afr, hb, qacc, 0, 0, 0);
                }
                if (lm == 0) {
#pragma unroll
                    for (int rr = 0; rr < 4; ++rr) {
                        int o = w * 16 + lk * 4 + rr;
                        qc_s[o] = qacc[rr] + bq[o] + cb[o];
                    }
                }
            }
            __syncthreads();
#pragma unroll
            for (int p = 0; p < 2; ++p) {
                int t0 = (w + 8 * p) * 16;
                bf16x8 bfr;
#pragma unroll
                for (int j = 0; j < 8; ++j) bfr[j] = (short)f2b(cum_s[t0 + lm + 8 * lk + j]);
                float e = 0.f;
                int t = t0 + lm;
#pragma unroll
                for (int m = 0; m < 8; ++m) {
                    bf16x8 afr = *(const bf16x8*)(cwp + (((size_t)(m * 64 + l)) << 3));
                    f32x4 acc = {0.f,0.f,0.f,0.f};
                    acc = __builtin_amdgcn_mfma_f32_16x16x32_bf16(afr, bfr, acc, 0, 0, 0);
                    const float* ep = enc + ((size_t)t * 32 + b) * 128 + m * 16 + 4 * lk;
                    f32x4 ev = *(const f32x4*)ep;
#pragma unroll
                    for (int rr = 0; rr < 4; ++rr) {
                        int h = m * 16 + 4 * lk + rr;
                        e += ftanh(qc_s[h] + ev[rr] + acc[rr]) * av[h];
                    }
                }
                e += __shfl_xor(e, 16); e += __shfl_xor(e, 32);
                if (l < 16) e_s[t0 + l] = e;
            }
            __syncthreads();
            if (tid < 256) {
                float e = e_s[tid], mm = e;
#pragma unroll
                for (int off = 1; off < 64; off <<= 1) mm = fmaxf(mm, __shfl_xor(mm, off));
                if ((tid & 63) == 0) redm[tid >> 6] = mm;
            }
            __syncthreads();
            if (tid < 256) {
                float mm = fmaxf(fmaxf(redm[0], redm[1]), fmaxf(redm[2], redm[3]));
                float ex = __expf(e_s[tid] - mm);
                a_s[tid] = ex;
                float s = ex;
#pragma unroll
                for (int off = 1; off < 64; off <<= 1) s += __shfl_xor(s, off);
                if ((tid & 63) == 0) redm[8 + (tid >> 6)] = s;
            }
            __syncthreads();
            if (tid < 256) {
                float s = redm[8] + redm[9] + redm[10] + redm[11];
                float a = __fdividef(a_s[tid], s);
                a_s[tid] = a;
                cum_s[15 + tid] += a;
                align_f[((size_t)f * 32 + b) * 256 + tid] = a;
            }
            __syncthreads();
            {
                int h = tid & 127, tq = tid >> 7;
                float acc = 0.f;
                const float* ep = enc + ((size_t)(tq * 64) * 32 + b) * 128 + h;
#pragma unroll 4
                for (int t2 = 0; t2 < 64; ++t2)
                    acc += a_s[tq * 64 + t2] * ep[(size_t)t2 * 4096];
                ctx_p[tq][h] = acc;
            }
            __syncthreads();
            if (tid < 32) {
                u64 pack = 0;
#pragma unroll
                for (int j = 0; j < 4; ++j) {
                    int h = tid * 4 + j;
                    float s2 = ctx_p[0][h] + ctx_p[1][h] + ctx_p[2][h] + ctx_p[3][h];
                    pack |= (u64)f2b(s2) << (16 * j);
                }
                st_sys_u64((u64*)(ctx_bf + ((size_t)(f + 1) * 32 + b) * 128 + tid * 4), pack);
            }
        }
        gridbar(bar_arr, bar_rel, 2 * f + 2);
    }
    // tail: GEMM2+cell2 for step 127
    gemm2cell(128, tid, l, w, lm, lk, r, w2f, h1n, ctx_bf, spk_bf, h2n,
              b2l, c2_s, red, g_s);
}

// ------------------------------------------------- final projection --------
__global__ __launch_bounds__(512) void k_outproj(
    const unsigned short* __restrict__ Wp,
    const unsigned short* __restrict__ h2n, const unsigned short* __restrict__ ctxb,
    const unsigned short* __restrict__ spkb,
    const float* __restrict__ ob, float* __restrict__ frames)
{
    int tid = threadIdx.x, l = tid & 63, w = tid >> 6;
    int lm = l & 15, lk = l >> 4;
    int fb0 = blockIdx.x * 16;
    int fb = fb0 + lm, fslab = (fb >> 5) + 1, b = fb & 31;
    f32x4 acc = {0.f, 0.f, 0.f, 0.f};
    const unsigned short* wp = Wp + (((size_t)w * 40) << 9) + (l << 3);
    for (int kc = 0; kc < 40; ++kc) {
        int kg = kc << 5;
        bf16x8 bb;
        if (kg < 1024)
            bb = ldh8(h2n, fslab, kg + 8 * lk, b);
        else if (kg < 1152)
            bb = *(const bf16x8*)(ctxb + ((size_t)fslab * 32 + b) * 128 + (kg - 1024) + 8 * lk);
        else
            bb = *(const bf16x8*)(spkb + (size_t)b * 128 + (kg - 1152) + 8 * lk);
        bf16x8 aa = *(const bf16x8*)wp;
        acc = __builtin_amdgcn_mfma_f32_16x16x32_bf16(aa, bb, acc, 0, 0, 0);
        wp += 512;
    }
    f32x4 ov = *(const f32x4*)(ob + w * 16 + 4 * lk);
    *(f32x4*)(frames + (size_t)fb * 128 + w * 16 + 4 * lk) = acc + ov;
}

// ------------------------------------------------- stop projection ---------
__global__ __launch_bounds__(256) void k_stop(
    const unsigned short* __restrict__ h2n, const unsigned short* __restrict__ spkb,
    const unsigned short* __restrict__ swb, const float* __restrict__ sb,
    float* __restrict__ stop)
{
    int tid = threadIdx.x;
    int fb = blockIdx.x * 32 + (tid >> 3);
    int fslab = (fb >> 5) + 1, b = fb & 31;
    int kb = (tid & 7) * 8;
    float acc = 0.f;
    for (int i = 0; i < 18; ++i) {
        int k = kb + 64 * i;
        bf16x8 xv;
        if (k < 1024) xv = ldh8(h2n, fslab, k, b);
        else          xv = *(const bf16x8*)(spkb + (size_t)b * 128 + (k - 1024));
        bf16x8 wv = *(const bf16x8*)(swb + k);
#pragma unroll
        for (int j = 0; j < 8; ++j)
            acc += b2f((unsigned short)xv[j]) * b2f((unsigned short)wv[j]);
    }
    acc += __shfl_xor(acc, 1); acc += __shfl_xor(acc, 2); acc += __shfl_xor(acc, 4);
    if ((tid & 7) == 0) stop[fb] = acc + sb[0];
}

// ------------------------------------------------------------------ host ----
extern "C" void kernel_launch(void* const* d_in, const int* in_sizes, int n_in,
                              void* d_out, int out_size, void* d_ws, size_t ws_size,
                              hipStream_t stream)
{
    const float* enc  = (const float*)d_in[0];
    const float* spk  = (const float*)d_in[2];
    const float* tf   = (const float*)d_in[3];
    const float* pw1  = (const float*)d_in[4];
    const float* pb1  = (const float*)d_in[5];
    const float* pw2  = (const float*)d_in[6];
    const float* pb2  = (const float*)d_in[7];
    const float* w1ih = (const float*)d_in[8];
    const float* w1hh = (const float*)d_in[9];
    const float* b1l  = (const float*)d_in[10];
    const float* w2ih = (const float*)d_in[11];
    const float* w2hh = (const float*)d_in[12];
    const float* b2l  = (const float*)d_in[13];
    const float* cw   = (const float*)d_in[14];
    const float* cb   = (const float*)d_in[15];
    const float* wq   = (const float*)d_in[16];
    const float* bq   = (const float*)d_in[17];
    const float* av   = (const float*)d_in[18];
    const float* ow   = (const float*)d_in[19];
    const float* ob   = (const float*)d_in[20];
    const float* sw   = (const float*)d_in[21];
    const float* sb   = (const float*)d_in[22];

    char* base = (char*)d_ws;
    size_t off = 0;
    auto take = [&](size_t bytes) {
        char* p = base + off;
        off += (bytes + 255) & ~(size_t)255;
        return p;
    };
    unsigned short* W1p    = (unsigned short*)take(4096u * 1536 * 2);
    unsigned short* W2p    = (unsigned short*)take(4096u * 2304 * 2);
    unsigned short* outWp  = (unsigned short*)take(128u * 1280 * 2);
    unsigned short* pw1p   = (unsigned short*)take(256u * 128 * 2);
    unsigned short* pw2p   = (unsigned short*)take(256u * 256 * 2);
    unsigned short* cwp    = (unsigned short*)take(512u * 8 * 2);
    unsigned short* wqp    = (unsigned short*)take(128u * 1024 * 2);
    unsigned short* sw_bf  = (unsigned short*)take(1152u * 2);
    unsigned short* spk_bf = (unsigned short*)take(32u * 128 * 2);
    unsigned short* fin_bf = (unsigned short*)take(4096u * 128 * 2);
    unsigned short* P1_bf  = (unsigned short*)take(4096u * 256 * 2);
    unsigned short* p_bf   = (unsigned short*)take(4096u * 256 * 2);
    unsigned short* h1n    = (unsigned short*)take(129u * 32768 * 2);
    unsigned short* h2n    = (unsigned short*)take(129u * 32768 * 2);
    unsigned short* ctx_bfs= (unsigned short*)take(129u * 32 * 128 * 2);
    int* bar = (int*)take((256 * FLAG_STRIDE + 8 * FLAG_STRIDE) * 4);
    int* bar_arr = bar;
    int* bar_rel = bar + 256 * FLAG_STRIDE;

    float* frames_out = (float*)d_out;                       // [F][B][128]
    float* stop_out   = frames_out + (size_t)Ff * Bb * Cc;   // [F][B]
    float* align_out  = stop_out + Ff * Bb;                  // [F][B][256]

    // ---- prologue: weight repacks + converts + state init ----
    k_repack<<<dim3(3072), dim3(256), 0, stream>>>(w1ih, w1hh, 512, 1536, 256 * 48 * 64, 1, W1p);
    k_repack<<<dim3(4608), dim3(256), 0, stream>>>(w2ih, w2hh, 1280, 2304, 256 * 72 * 64, 1, W2p);
    k_repack<<<dim3((8 * 40 * 64 + 255) / 256), dim3(256), 0, stream>>>(ow, ow, 1280, 1280, 8 * 40 * 64, 0, outWp);
    k_repack<<<dim3((16 * 4 * 64 + 255) / 256), dim3(256), 0, stream>>>(pw1, pw1, 128, 128, 16 * 4 * 64, 0, pw1p);
    k_repack<<<dim3((16 * 8 * 64 + 255) / 256), dim3(256), 0, stream>>>(pw2, pw2, 256, 256, 16 * 8 * 64, 0, pw2p);
    k_repack<<<dim3((8 * 32 * 64 + 255) / 256), dim3(256), 0, stream>>>(wq, wq, 1024, 1024, 8 * 32 * 64, 0, wqp);
    k_cwp<<<dim3(2), dim3(256), 0, stream>>>(cw, cwp);
    k_cvt<<<dim3(16), dim3(256), 0, stream>>>(spk, spk_bf, 4096);
    k_cvt<<<dim3(5), dim3(256), 0, stream>>>(sw, sw_bf, 1152);
    k_fin<<<dim3(2048), dim3(256), 0, stream>>>(tf, fin_bf);

    hipMemsetAsync(bar, 0, (256 * FLAG_STRIDE + 8 * FLAG_STRIDE) * 4, stream);
    hipMemsetAsync(h1n, 0, 32768u * 2, stream);          // h1 state slab 0 = 0
    hipMemsetAsync(h2n, 0, 32768u * 2, stream);          // h2 state slab 0 = 0
    hipMemsetAsync(ctx_bfs, 0, 32u * 128 * 2, stream);   // ctx slab 0 = 0

    // prenet (both layers, all frames)
    k_prelayer<<<dim3(256), dim3(1024), 0, stream>>>(pw1p, 4, fin_bf, 128, pb1, P1_bf);
    k_prelayer<<<dim3(256), dim3(1024), 0, stream>>>(pw2p, 8, P1_bf, 256, pb2, p_bf);

    // ---- persistent decode (both LSTMs + attention, all 128 steps) ----
    k_persist<<<dim3(256), dim3(512), 0, stream>>>(
        W1p, W2p, p_bf, spk_bf, h1n, h2n, ctx_bfs,
        b1l, b2l, enc, wqp, bq, cwp, cb, av,
        align_out, bar_arr, bar_rel);

    // ---- epilogue ----
    k_outproj<<<dim3(256), dim3(512), 0, stream>>>(
        outWp, h2n, ctx_bfs, spk_bf, ob, frames_out);
    k_stop<<<dim3(128), dim3(256), 0, stream>>>(
        h2n, spk_bf, sw_bf, sb, stop_out);
}

// Round 8
// 3729.762 us; speedup vs baseline: 1.3467x; 1.3467x over previous
//
#include <hip/hip_runtime.h>

#define Tt 256
#define Bb 32
#define Ff 128
#define Cc 128
#define HA 128
#define LS 1024
#define PR 256
#define SP 128
#define KC 31
#define FLAG_STRIDE 16

typedef __attribute__((ext_vector_type(8))) short bf16x8;
typedef __attribute__((ext_vector_type(4))) short short4v;
typedef __attribute__((ext_vector_type(4))) float f32x4;
typedef unsigned long long u64;

__device__ __forceinline__ unsigned short f2b(float f) {
    unsigned u = __float_as_uint(f);
    unsigned r = (u + 0x7fff + ((u >> 16) & 1)) >> 16;
    return (unsigned short)r;
}
__device__ __forceinline__ float b2f(unsigned short s) {
    return __uint_as_float(((unsigned)s) << 16);
}
__device__ __forceinline__ float sigm(float x) { return __fdividef(1.0f, 1.0f + __expf(-x)); }
__device__ __forceinline__ float ftanh(float x) {
    x = fminf(10.0f, fmaxf(-10.0f, x));
    float t = __expf(2.0f * x);
    return __fdividef(t - 1.0f, t + 1.0f);
}
__device__ __forceinline__ void st_sys_u64(u64* p, u64 v) {
    __hip_atomic_store(p, v, __ATOMIC_RELAXED, __HIP_MEMORY_SCOPE_SYSTEM);
}

// h state layout: [slab][u4=unit>>2][b][4 units] u16; block r sole producer of
// group u4==r (single-producer 64B lines; consumers use plain cached loads on
// cold slab-f addresses).
__device__ __forceinline__ bf16x8 ldh8(const unsigned short* base, int slab, int kb, int b) {
    const u64* p = (const u64*)(base + (size_t)slab * 32768 + (size_t)(kb >> 2) * 128 + b * 4);
    union { bf16x8 v; u64 q[2]; } u;
    u.q[0] = p[0];
    u.q[1] = p[32];
    return u.v;
}

// ---------------------------------------------------------------- repack ----
__global__ __launch_bounds__(256) void k_repack(
    const float* __restrict__ srcA, const float* __restrict__ srcB,
    int kSplit, int K, int total, int interleave, unsigned short* __restrict__ dst)
{
    int t = blockIdx.x * 256 + threadIdx.x;
    if (t >= total) return;
    int l = t & 63, frag = t >> 6;
    int nkc = K >> 5;
    int rt = frag / nkc, kc = frag - rt * nkc;
    int lm = l & 15;
    int g = interleave ? ((lm >> 2) * 1024 + rt * 4 + (lm & 3)) : (rt * 16 + lm);
    int kb = kc * 32 + 8 * (l >> 4);
#pragma unroll
    for (int j = 0; j < 8; ++j) {
        int k = kb + j;
        float f = (k < kSplit) ? srcA[(size_t)g * kSplit + k]
                               : srcB[(size_t)g * (K - kSplit) + (k - kSplit)];
        dst[(size_t)t * 8 + j] = f2b(f);
    }
}

__global__ __launch_bounds__(256) void k_cwp(
    const float* __restrict__ cw, unsigned short* __restrict__ dst)
{
    int t = blockIdx.x * 256 + threadIdx.x;
    if (t >= 512) return;
    int l = t & 63, r = t >> 6;
    int h = r * 16 + (l & 15);
    int kb = 8 * (l >> 4);
#pragma unroll
    for (int j = 0; j < 8; ++j) {
        int k = kb + j;
        dst[(size_t)t * 8 + j] = (k < KC) ? f2b(cw[h * KC + k]) : 0;
    }
}

__global__ __launch_bounds__(256) void k_cvt(
    const float* __restrict__ src, unsigned short* __restrict__ dst, int n)
{
    int i = blockIdx.x * 256 + threadIdx.x;
    if (i < n) dst[i] = f2b(src[i]);
}

// enc f32 [t][b][h] -> bf16 [b][t][h]: per-attention-block contiguous 64 KB
// slice (L2-friendly; f32 enc's 4 MB exactly filled an XCD L2 and thrashed it)
__global__ __launch_bounds__(256) void k_encb(
    const float* __restrict__ enc, unsigned short* __restrict__ out)
{
    int i = blockIdx.x * 256 + threadIdx.x;      // i = b*32768 + t*128 + h
    if (i >= Tt * Bb * HA) return;
    int h = i & 127, t = (i >> 7) & 255, b = i >> 15;
    out[i] = f2b(enc[((size_t)t * 32 + b) * 128 + h]);
}

__global__ __launch_bounds__(256) void k_fin(
    const float* __restrict__ tf, unsigned short* __restrict__ dst)
{
    int i = blockIdx.x * 256 + threadIdx.x;
    if (i >= Ff * Bb * Cc) return;
    int fb = i >> 7, cpos = i & 127;
    int f = fb >> 5, b = fb & 31;
    float v = (f == 0) ? -9.210340371976182f : tf[((size_t)(f - 1) * Bb + b) * Cc + cpos];
    dst[i] = f2b(v);
}

// ------------------------------------------------- prenet layer (MFMA) -----
__global__ __launch_bounds__(1024) void k_prelayer(
    const unsigned short* __restrict__ Wp, int nkc,
    const unsigned short* __restrict__ X, int rs,
    const float* __restrict__ bias, unsigned short* __restrict__ Y)
{
    int tid = threadIdx.x, l = tid & 63, w = tid >> 6;
    int lm = l & 15, lk = l >> 4;
    int fb0 = blockIdx.x * 16;
    f32x4 acc = {0.f, 0.f, 0.f, 0.f};
    const unsigned short* wp = Wp + (((size_t)w * nkc) << 9) + (l << 3);
    for (int kc = 0; kc < nkc; ++kc) {
        bf16x8 bb = *(const bf16x8*)(X + (size_t)(fb0 + lm) * rs + (kc << 5) + 8 * lk);
        bf16x8 aa = *(const bf16x8*)wp;
        acc = __builtin_amdgcn_mfma_f32_16x16x32_bf16(aa, bb, acc, 0, 0, 0);
        wp += 512;
    }
    short4v o;
#pragma unroll
    for (int rr = 0; rr < 4; ++rr) {
        float v = acc[rr] + bias[w * 16 + 4 * lk + rr];
        o[rr] = (short)f2b(fmaxf(v, 0.f));
    }
    *(short4v*)(Y + (size_t)(fb0 + lm) * 256 + w * 16 + 4 * lk) = o;
}

// ------------------------------------------------- grid barrier ------------
__device__ __forceinline__ int poll_flag(int* p, int it) {
    if ((it & 63) == 63)
        return __hip_atomic_fetch_add(p, 0, __ATOMIC_RELAXED, __HIP_MEMORY_SCOPE_SYSTEM);
    return __hip_atomic_load(p, __ATOMIC_RELAXED, __HIP_MEMORY_SCOPE_SYSTEM);
}
__device__ __forceinline__ void gridbar(int* arr, int* rel, int gen)
{
    __syncthreads();
    if (blockIdx.x == 0) {
        int tid = threadIdx.x;
        if (tid >= 1 && tid < 256) {
            int cnt = 0;
            while (poll_flag(&arr[tid * FLAG_STRIDE], cnt) < gen) {
                __builtin_amdgcn_s_sleep(2);
                if (++cnt > 2000000) break;
            }
        }
        __syncthreads();
        if (tid < 8)
            __hip_atomic_store(&rel[tid * FLAG_STRIDE], gen, __ATOMIC_RELAXED,
                               __HIP_MEMORY_SCOPE_SYSTEM);
    } else {
        if (threadIdx.x == 0) {
            __hip_atomic_store(&arr[blockIdx.x * FLAG_STRIDE], gen, __ATOMIC_RELAXED,
                               __HIP_MEMORY_SCOPE_SYSTEM);
            int cnt = 0;
            while (poll_flag(&rel[(blockIdx.x & 7) * FLAG_STRIDE], cnt) < gen) {
                __builtin_amdgcn_s_sleep(2);
                if (++cnt > 2000000) break;
            }
        }
    }
    __syncthreads();
}

// ------------------------------------------------- X fragment loaders ------
// Plain cached loads (R6-proven): mutable slabs are cold f-indexed addresses
// with single-producer lines -> coherent fill from the coherence point.
__device__ __forceinline__ bf16x8 xfrag1(
    int k, int f, int row,
    const unsigned short* p_bf, const unsigned short* ctx_bf,
    const unsigned short* spk_bf, const unsigned short* h1n)
{
    if (k < 256)  return *(const bf16x8*)(p_bf + ((size_t)(f * 32 + row)) * 256 + k);
    if (k < 384)  return *(const bf16x8*)(ctx_bf + ((size_t)(f * 32 + row)) * 128 + (k - 256));
    if (k < 512)  return *(const bf16x8*)(spk_bf + (size_t)row * 128 + (k - 384));
    return ldh8(h1n, f, k - 512, row);
}
__device__ __forceinline__ bf16x8 xfrag2(
    int k, int f, int row,
    const unsigned short* h1n, const unsigned short* ctx_bf,
    const unsigned short* spk_bf, const unsigned short* h2n)
{
    if (k < 1024) return ldh8(h1n, f, k, row);
    if (k < 1152) return *(const bf16x8*)(ctx_bf + ((size_t)(f * 32 + row)) * 128 + (k - 1024));
    if (k < 1280) return *(const bf16x8*)(spk_bf + (size_t)row * 128 + (k - 1152));
    return ldh8(h2n, f - 1, k - 1280, row);
}

// ------------------------------------------------- GEMM2 + cell2 (inline) --
__device__ __forceinline__ void gemm2cell(
    int f, int tid, int l, int w, int lm, int lk, int r,
    const bf16x8 (&w2f)[9],
    const unsigned short* h1n, const unsigned short* ctx_bf,
    const unsigned short* spk_bf, unsigned short* h2n,
    const float* b2l, float* c2_s,
    f32x4 (*red)[2][64], float (*g_s)[4][16][4])
{
    f32x4 a0 = {0.f,0.f,0.f,0.f}, a1 = {0.f,0.f,0.f,0.f};
#pragma unroll
    for (int i = 0; i < 9; ++i) {
        int kk = (w * 9 + i) * 32 + 8 * lk;
        bf16x8 b0 = xfrag2(kk, f, lm, h1n, ctx_bf, spk_bf, h2n);
        bf16x8 b1 = xfrag2(kk, f, 16 + lm, h1n, ctx_bf, spk_bf, h2n);
        a0 = __builtin_amdgcn_mfma_f32_16x16x32_bf16(w2f[i], b0, a0, 0, 0, 0);
        a1 = __builtin_amdgcn_mfma_f32_16x16x32_bf16(w2f[i], b1, a1, 0, 0, 0);
    }
    __syncthreads();                 // cell1 done with g_s / red consumed
    red[w][0][l] = a0; red[w][1][l] = a1;
    __syncthreads();
    if (tid < 128) {
        int ct = tid >> 6, ll = tid & 63;
        f32x4 s = red[0][ct][ll];
#pragma unroll
        for (int ww = 1; ww < 8; ++ww) s += red[ww][ct][ll];
        int llm = ll & 15, llk = ll >> 4;
#pragma unroll
        for (int rr = 0; rr < 4; ++rr) g_s[ct][llk][llm][rr] = s[rr];
    }
    __syncthreads();
    if (tid < 32) {
        int b = tid, ct = b >> 4, bl = b & 15;
        u64 pack = 0;
#pragma unroll
        for (int v = 0; v < 4; ++v) {
            int u = r * 4 + v;
            float gi = g_s[ct][0][bl][v] + b2l[u];
            float gf = g_s[ct][1][bl][v] + b2l[1024 + u];
            float gg = g_s[ct][2][bl][v] + b2l[2048 + u];
            float go = g_s[ct][3][bl][v] + b2l[3072 + u];
            float cc = sigm(gf) * c2_s[b + 32 * v] + sigm(gi) * ftanh(gg);
            c2_s[b + 32 * v] = cc;
            pack |= (u64)f2b(sigm(go) * ftanh(cc)) << (16 * v);
        }
        st_sys_u64((u64*)(h2n + (size_t)f * 32768 + (size_t)r * 128 + b * 4), pack);
    }
}

// ------------------------------------------------- persistent decoder ------
__global__ __launch_bounds__(512) void k_persist(
    const unsigned short* __restrict__ W1p, const unsigned short* __restrict__ W2p,
    const unsigned short* __restrict__ p_bf, const unsigned short* __restrict__ spk_bf,
    unsigned short* __restrict__ h1n, unsigned short* __restrict__ h2n,
    unsigned short* __restrict__ ctx_bf,
    const float* __restrict__ b1l, const float* __restrict__ b2l,
    const unsigned short* __restrict__ encb, const unsigned short* __restrict__ wq_bf,
    const float* __restrict__ bq, const unsigned short* __restrict__ cwp,
    const float* __restrict__ cb, const float* __restrict__ av,
    float* __restrict__ align_f, int* __restrict__ bar_arr, int* __restrict__ bar_rel)
{
    const int tid = threadIdx.x;
    const int l = tid & 63, w = tid >> 6;
    const int lm = l & 15, lk = l >> 4;
    const int r = blockIdx.x;

    bf16x8 w1f[6], w2f[9];
#pragma unroll
    for (int i = 0; i < 6; ++i)
        w1f[i] = *(const bf16x8*)(W1p + (((size_t)(r * 48 + w * 6 + i)) << 9) + (l << 3));
#pragma unroll
    for (int i = 0; i < 9; ++i)
        w2f[i] = *(const bf16x8*)(W2p + (((size_t)(r * 72 + w * 9 + i)) << 9) + (l << 3));

    __shared__ f32x4 red[8][2][64];
    __shared__ float g_s[2][4][16][4];
    __shared__ float c1_s[128], c2_s[128];
    __shared__ float h1_sh[1024];
    __shared__ float qc_s[128];
    __shared__ float cum_s[292];
    __shared__ float e_s[256], a_s[256];
    __shared__ float ctx_p[4][128];
    __shared__ float redm[16];

    if (tid < 128) { c1_s[tid] = 0.f; c2_s[tid] = 0.f; }
    for (int i = tid; i < 292; i += 512) cum_s[i] = 0.f;
    __syncthreads();

    for (int f = 0; f < 128; ++f) {
        // ---------------- phase 1: GEMM1[f]+cell1, GEMM2[f-1]+cell2 --------
        {
            f32x4 a0 = {0.f,0.f,0.f,0.f}, a1 = {0.f,0.f,0.f,0.f};
#pragma unroll
            for (int i = 0; i < 6; ++i) {
                int kk = (w * 6 + i) * 32 + 8 * lk;
                bf16x8 b0 = xfrag1(kk, f, lm, p_bf, ctx_bf, spk_bf, h1n);
                bf16x8 b1 = xfrag1(kk, f, 16 + lm, p_bf, ctx_bf, spk_bf, h1n);
                a0 = __builtin_amdgcn_mfma_f32_16x16x32_bf16(w1f[i], b0, a0, 0, 0, 0);
                a1 = __builtin_amdgcn_mfma_f32_16x16x32_bf16(w1f[i], b1, a1, 0, 0, 0);
            }
            red[w][0][l] = a0; red[w][1][l] = a1;
        }
        __syncthreads();
        if (tid < 128) {
            int ct = tid >> 6, ll = tid & 63;
            f32x4 s = red[0][ct][ll];
#pragma unroll
            for (int ww = 1; ww < 8; ++ww) s += red[ww][ct][ll];
            int llm = ll & 15, llk = ll >> 4;
#pragma unroll
            for (int rr = 0; rr < 4; ++rr) g_s[ct][llk][llm][rr] = s[rr];
        }
        __syncthreads();
        if (tid < 32) {
            int b = tid, ct = b >> 4, bl = b & 15;
            u64 pack = 0;
#pragma unroll
            for (int v = 0; v < 4; ++v) {
                int u = r * 4 + v;
                float gi = g_s[ct][0][bl][v] + b1l[u];
                float gf = g_s[ct][1][bl][v] + b1l[1024 + u];
                float gg = g_s[ct][2][bl][v] + b1l[2048 + u];
                float go = g_s[ct][3][bl][v] + b1l[3072 + u];
                float cc = sigm(gf) * c1_s[b + 32 * v] + sigm(gi) * ftanh(gg);
                c1_s[b + 32 * v] = cc;
                pack |= (u64)f2b(sigm(go) * ftanh(cc)) << (16 * v);
            }
            st_sys_u64((u64*)(h1n + (size_t)(f + 1) * 32768 + (size_t)r * 128 + b * 4), pack);
        }
        if (f >= 1)
            gemm2cell(f, tid, l, w, lm, lk, r, w2f, h1n, ctx_bf, spk_bf, h2n,
                      b2l, c2_s, red, g_s);
        gridbar(bar_arr, bar_rel, 2 * f + 1);

        // ---------------- phase 2: attention (blocks 0..31) ----------------
        if (r < 32) {
            const int b = r;
            if (tid < 256) {          // unpack h1[f+1] row b (cold cached lines)
                u64 q = *(const u64*)(h1n + (size_t)(f + 1) * 32768 + (size_t)tid * 128 + b * 4);
#pragma unroll
                for (int j = 0; j < 4; ++j)
                    h1_sh[tid * 4 + j] = b2f((unsigned short)(q >> (16 * j)));
            }
            __syncthreads();
            // q = Wq.h1 + bq (+cb folded)
            {
                int o = tid >> 2, kq = tid & 3;
                const f32x4* hh = (const f32x4*)(h1_sh + kq * 256);
                const unsigned short* wr = wq_bf + (size_t)o * 1024 + kq * 256;
                float acc = 0.f;
#pragma unroll 4
                for (int i2 = 0; i2 < 32; ++i2) {
                    bf16x8 wv = *(const bf16x8*)(wr + i2 * 8);
                    f32x4 x0 = hh[i2 * 2], x1 = hh[i2 * 2 + 1];
                    acc += b2f((unsigned short)wv[0]) * x0[0] + b2f((unsigned short)wv[1]) * x0[1]
                         + b2f((unsigned short)wv[2]) * x0[2] + b2f((unsigned short)wv[3]) * x0[3]
                         + b2f((unsigned short)wv[4]) * x1[0] + b2f((unsigned short)wv[5]) * x1[1]
                         + b2f((unsigned short)wv[6]) * x1[2] + b2f((unsigned short)wv[7]) * x1[3];
                }
                acc += __shfl_xor(acc, 1); acc += __shfl_xor(acc, 2);
                if (kq == 0) qc_s[o] = acc + bq[o] + cb[o];
            }
            __syncthreads();
#pragma unroll
            for (int p = 0; p < 2; ++p) {
                int t0 = (w + 8 * p) * 16;
                bf16x8 bfr;
#pragma unroll
                for (int j = 0; j < 8; ++j) bfr[j] = (short)f2b(cum_s[t0 + lm + 8 * lk + j]);
                float e = 0.f;
                int t = t0 + lm;
#pragma unroll
                for (int m = 0; m < 8; ++m) {
                    bf16x8 afr = *(const bf16x8*)(cwp + (((size_t)(m * 64 + l)) << 3));
                    f32x4 acc = {0.f,0.f,0.f,0.f};
                    acc = __builtin_amdgcn_mfma_f32_16x16x32_bf16(afr, bfr, acc, 0, 0, 0);
                    const unsigned short* ep = encb + ((size_t)b << 15) + (size_t)t * 128 + m * 16 + 4 * lk;
                    short4v ev4 = *(const short4v*)ep;
#pragma unroll
                    for (int rr = 0; rr < 4; ++rr) {
                        int h = m * 16 + 4 * lk + rr;
                        e += ftanh(qc_s[h] + b2f((unsigned short)ev4[rr]) + acc[rr]) * av[h];
                    }
                }
                e += __shfl_xor(e, 16); e += __shfl_xor(e, 32);
                if (l < 16) e_s[t0 + l] = e;
            }
            __syncthreads();
            if (tid < 256) {
                float e = e_s[tid], mm = e;
#pragma unroll
                for (int off = 1; off < 64; off <<= 1) mm = fmaxf(mm, __shfl_xor(mm, off));
                if ((tid & 63) == 0) redm[tid >> 6] = mm;
            }
            __syncthreads();
            if (tid < 256) {
                float mm = fmaxf(fmaxf(redm[0], redm[1]), fmaxf(redm[2], redm[3]));
                float ex = __expf(e_s[tid] - mm);
                a_s[tid] = ex;
                float s = ex;
#pragma unroll
                for (int off = 1; off < 64; off <<= 1) s += __shfl_xor(s, off);
                if ((tid & 63) == 0) redm[8 + (tid >> 6)] = s;
            }
            __syncthreads();
            if (tid < 256) {
                float s = redm[8] + redm[9] + redm[10] + redm[11];
                float a = __fdividef(a_s[tid], s);
                a_s[tid] = a;
                cum_s[15 + tid] += a;
                align_f[((size_t)f * 32 + b) * 256 + tid] = a;
            }
            __syncthreads();
            {
                int h = tid & 127, tq = tid >> 7;
                float acc = 0.f;
                const unsigned short* ep = encb + ((size_t)b << 15) + (size_t)(tq * 64) * 128 + h;
#pragma unroll 4
                for (int t2 = 0; t2 < 64; ++t2)
                    acc += a_s[tq * 64 + t2] * b2f(ep[(size_t)t2 * 128]);
                ctx_p[tq][h] = acc;
            }
            __syncthreads();
            if (tid < 32) {
                u64 pack = 0;
#pragma unroll
                for (int j = 0; j < 4; ++j) {
                    int h = tid * 4 + j;
                    float s2 = ctx_p[0][h] + ctx_p[1][h] + ctx_p[2][h] + ctx_p[3][h];
                    pack |= (u64)f2b(s2) << (16 * j);
                }
                st_sys_u64((u64*)(ctx_bf + ((size_t)(f + 1) * 32 + b) * 128 + tid * 4), pack);
            }
        }
        gridbar(bar_arr, bar_rel, 2 * f + 2);
    }
    // tail: GEMM2+cell2 for step 127
    gemm2cell(128, tid, l, w, lm, lk, r, w2f, h1n, ctx_bf, spk_bf, h2n,
              b2l, c2_s, red, g_s);
}

// ------------------------------------------------- final projection --------
__global__ __launch_bounds__(512) void k_outproj(
    const unsigned short* __restrict__ Wp,
    const unsigned short* __restrict__ h2n, const unsigned short* __restrict__ ctxb,
    const unsigned short* __restrict__ spkb,
    const float* __restrict__ ob, float* __restrict__ frames)
{
    int tid = threadIdx.x, l = tid & 63, w = tid >> 6;
    int lm = l & 15, lk = l >> 4;
    int fb0 = blockIdx.x * 16;
    int fb = fb0 + lm, fslab = (fb >> 5) + 1, b = fb & 31;
    f32x4 acc = {0.f, 0.f, 0.f, 0.f};
    const unsigned short* wp = Wp + (((size_t)w * 40) << 9) + (l << 3);
    for (int kc = 0; kc < 40; ++kc) {
        int kg = kc << 5;
        bf16x8 bb;
        if (kg < 1024)
            bb = ldh8(h2n, fslab, kg + 8 * lk, b);
        else if (kg < 1152)
            bb = *(const bf16x8*)(ctxb + ((size_t)fslab * 32 + b) * 128 + (kg - 1024) + 8 * lk);
        else
            bb = *(const bf16x8*)(spkb + (size_t)b * 128 + (kg - 1152) + 8 * lk);
        bf16x8 aa = *(const bf16x8*)wp;
        acc = __builtin_amdgcn_mfma_f32_16x16x32_bf16(aa, bb, acc, 0, 0, 0);
        wp += 512;
    }
    f32x4 ov = *(const f32x4*)(ob + w * 16 + 4 * lk);
    *(f32x4*)(frames + (size_t)fb * 128 + w * 16 + 4 * lk) = acc + ov;
}

// ------------------------------------------------- stop projection ---------
__global__ __launch_bounds__(256) void k_stop(
    const unsigned short* __restrict__ h2n, const unsigned short* __restrict__ spkb,
    const unsigned short* __restrict__ swb, const float* __restrict__ sb,
    float* __restrict__ stop)
{
    int tid = threadIdx.x;
    int fb = blockIdx.x * 32 + (tid >> 3);
    int fslab = (fb >> 5) + 1, b = fb & 31;
    int kb = (tid & 7) * 8;
    float acc = 0.f;
    for (int i = 0; i < 18; ++i) {
        int k = kb + 64 * i;
        bf16x8 xv;
        if (k < 1024) xv = ldh8(h2n, fslab, k, b);
        else          xv = *(const bf16x8*)(spkb + (size_t)b * 128 + (k - 1024));
        bf16x8 wv = *(const bf16x8*)(swb + k);
#pragma unroll
        for (int j = 0; j < 8; ++j)
            acc += b2f((unsigned short)xv[j]) * b2f((unsigned short)wv[j]);
    }
    acc += __shfl_xor(acc, 1); acc += __shfl_xor(acc, 2); acc += __shfl_xor(acc, 4);
    if ((tid & 7) == 0) stop[fb] = acc + sb[0];
}

// ------------------------------------------------------------------ host ----
extern "C" void kernel_launch(void* const* d_in, const int* in_sizes, int n_in,
                              void* d_out, int out_size, void* d_ws, size_t ws_size,
                              hipStream_t stream)
{
    const float* enc  = (const float*)d_in[0];
    const float* spk  = (const float*)d_in[2];
    const float* tf   = (const float*)d_in[3];
    const float* pw1  = (const float*)d_in[4];
    const float* pb1  = (const float*)d_in[5];
    const float* pw2  = (const float*)d_in[6];
    const float* pb2  = (const float*)d_in[7];
    const float* w1ih = (const float*)d_in[8];
    const float* w1hh = (const float*)d_in[9];
    const float* b1l  = (const float*)d_in[10];
    const float* w2ih = (const float*)d_in[11];
    const float* w2hh = (const float*)d_in[12];
    const float* b2l  = (const float*)d_in[13];
    const float* cw   = (const float*)d_in[14];
    const float* cb   = (const float*)d_in[15];
    const float* wq   = (const float*)d_in[16];
    const float* bq   = (const float*)d_in[17];
    const float* av   = (const float*)d_in[18];
    const float* ow   = (const float*)d_in[19];
    const float* ob   = (const float*)d_in[20];
    const float* sw   = (const float*)d_in[21];
    const float* sb   = (const float*)d_in[22];

    char* base = (char*)d_ws;
    size_t off = 0;
    auto take = [&](size_t bytes) {
        char* p = base + off;
        off += (bytes + 255) & ~(size_t)255;
        return p;
    };
    unsigned short* W1p    = (unsigned short*)take(4096u * 1536 * 2);
    unsigned short* W2p    = (unsigned short*)take(4096u * 2304 * 2);
    unsigned short* outWp  = (unsigned short*)take(128u * 1280 * 2);
    unsigned short* pw1p   = (unsigned short*)take(256u * 128 * 2);
    unsigned short* pw2p   = (unsigned short*)take(256u * 256 * 2);
    unsigned short* cwp    = (unsigned short*)take(512u * 8 * 2);
    unsigned short* wq_bf  = (unsigned short*)take(128u * 1024 * 2);
    unsigned short* sw_bf  = (unsigned short*)take(1152u * 2);
    unsigned short* spk_bf = (unsigned short*)take(32u * 128 * 2);
    unsigned short* enc_bf = (unsigned short*)take((size_t)Bb * Tt * HA * 2);
    unsigned short* fin_bf = (unsigned short*)take(4096u * 128 * 2);
    unsigned short* P1_bf  = (unsigned short*)take(4096u * 256 * 2);
    unsigned short* p_bf   = (unsigned short*)take(4096u * 256 * 2);
    unsigned short* h1n    = (unsigned short*)take(129u * 32768 * 2);
    unsigned short* h2n    = (unsigned short*)take(129u * 32768 * 2);
    unsigned short* ctx_bfs= (unsigned short*)take(129u * 32 * 128 * 2);
    int* bar = (int*)take((256 * FLAG_STRIDE + 8 * FLAG_STRIDE) * 4);
    int* bar_arr = bar;
    int* bar_rel = bar + 256 * FLAG_STRIDE;

    float* frames_out = (float*)d_out;                       // [F][B][128]
    float* stop_out   = frames_out + (size_t)Ff * Bb * Cc;   // [F][B]
    float* align_out  = stop_out + Ff * Bb;                  // [F][B][256]

    // ---- prologue: weight repacks + converts + state init ----
    k_repack<<<dim3(3072), dim3(256), 0, stream>>>(w1ih, w1hh, 512, 1536, 256 * 48 * 64, 1, W1p);
    k_repack<<<dim3(4608), dim3(256), 0, stream>>>(w2ih, w2hh, 1280, 2304, 256 * 72 * 64, 1, W2p);
    k_repack<<<dim3((8 * 40 * 64 + 255) / 256), dim3(256), 0, stream>>>(ow, ow, 1280, 1280, 8 * 40 * 64, 0, outWp);
    k_repack<<<dim3((16 * 4 * 64 + 255) / 256), dim3(256), 0, stream>>>(pw1, pw1, 128, 128, 16 * 4 * 64, 0, pw1p);
    k_repack<<<dim3((16 * 8 * 64 + 255) / 256), dim3(256), 0, stream>>>(pw2, pw2, 256, 256, 16 * 8 * 64, 0, pw2p);
    k_cwp<<<dim3(2), dim3(256), 0, stream>>>(cw, cwp);
    k_cvt<<<dim3(16), dim3(256), 0, stream>>>(spk, spk_bf, 4096);
    k_cvt<<<dim3(512), dim3(256), 0, stream>>>(wq, wq_bf, 131072);
    k_cvt<<<dim3(5), dim3(256), 0, stream>>>(sw, sw_bf, 1152);
    k_encb<<<dim3(4096), dim3(256), 0, stream>>>(enc, enc_bf);
    k_fin<<<dim3(2048), dim3(256), 0, stream>>>(tf, fin_bf);

    hipMemsetAsync(bar, 0, (256 * FLAG_STRIDE + 8 * FLAG_STRIDE) * 4, stream);
    hipMemsetAsync(h1n, 0, 32768u * 2, stream);          // h1 state slab 0 = 0
    hipMemsetAsync(h2n, 0, 32768u * 2, stream);          // h2 state slab 0 = 0
    hipMemsetAsync(ctx_bfs, 0, 32u * 128 * 2, stream);   // ctx slab 0 = 0

    // prenet (both layers, all frames)
    k_prelayer<<<dim3(256), dim3(1024), 0, stream>>>(pw1p, 4, fin_bf, 128, pb1, P1_bf);
    k_prelayer<<<dim3(256), dim3(1024), 0, stream>>>(pw2p, 8, P1_bf, 256, pb2, p_bf);

    // ---- persistent decode (both LSTMs + attention, all 128 steps) ----
    k_persist<<<dim3(256), dim3(512), 0, stream>>>(
        W1p, W2p, p_bf, spk_bf, h1n, h2n, ctx_bfs,
        b1l, b2l, enc_bf, wq_bf, bq, cwp, cb, av,
        align_out, bar_arr, bar_rel);

    // ---- epilogue ----
    k_outproj<<<dim3(256), dim3(512), 0, stream>>>(
        outWp, h2n, ctx_bfs, spk_bf, ob, frames_out);
    k_stop<<<dim3(128), dim3(256), 0, stream>>>(
        h2n, spk_bf, sw_bf, sb, stop_out);
}

// Round 9
// 3323.565 us; speedup vs baseline: 1.5113x; 1.1222x over previous
//
#include <hip/hip_runtime.h>

#define Tt 256
#define Bb 32
#define Ff 128
#define Cc 128
#define HA 128
#define LS 1024
#define PR 256
#define SP 128
#define KC 31
#define FLAG_STRIDE 16

typedef __attribute__((ext_vector_type(8))) short bf16x8;
typedef __attribute__((ext_vector_type(4))) short short4v;
typedef __attribute__((ext_vector_type(4))) float f32x4;
typedef unsigned long long u64;

__device__ __forceinline__ unsigned short f2b(float f) {
    unsigned u = __float_as_uint(f);
    unsigned r = (u + 0x7fff + ((u >> 16) & 1)) >> 16;
    return (unsigned short)r;
}
__device__ __forceinline__ float b2f(unsigned short s) {
    return __uint_as_float(((unsigned)s) << 16);
}
__device__ __forceinline__ float sigm(float x) { return __fdividef(1.0f, 1.0f + __expf(-x)); }
__device__ __forceinline__ float ftanh(float x) {
    x = fminf(10.0f, fmaxf(-10.0f, x));
    float t = __expf(2.0f * x);
    return __fdividef(t - 1.0f, t + 1.0f);
}
__device__ __forceinline__ void st_sys_u64(u64* p, u64 v) {
    __hip_atomic_store(p, v, __ATOMIC_RELAXED, __HIP_MEMORY_SCOPE_SYSTEM);
}

// h state layout: [slab][u4=unit>>2][b][4 units] u16; one tile-owner block is
// the SOLE producer of each u4 group (single-producer 64B lines; consumers use
// plain cached loads on cold slab-f addresses).
__device__ __forceinline__ bf16x8 ldh8(const unsigned short* base, int slab, int kb, int b) {
    const u64* p = (const u64*)(base + (size_t)slab * 32768 + (size_t)(kb >> 2) * 128 + b * 4);
    union { bf16x8 v; u64 q[2]; } u;
    u.q[0] = p[0];
    u.q[1] = p[32];
    return u.v;
}

// ---------------------------------------------------------------- repack ----
__global__ __launch_bounds__(256) void k_repack(
    const float* __restrict__ srcA, const float* __restrict__ srcB,
    int kSplit, int K, int total, int interleave, unsigned short* __restrict__ dst)
{
    int t = blockIdx.x * 256 + threadIdx.x;
    if (t >= total) return;
    int l = t & 63, frag = t >> 6;
    int nkc = K >> 5;
    int rt = frag / nkc, kc = frag - rt * nkc;
    int lm = l & 15;
    int g = interleave ? ((lm >> 2) * 1024 + rt * 4 + (lm & 3)) : (rt * 16 + lm);
    int kb = kc * 32 + 8 * (l >> 4);
#pragma unroll
    for (int j = 0; j < 8; ++j) {
        int k = kb + j;
        float f = (k < kSplit) ? srcA[(size_t)g * kSplit + k]
                               : srcB[(size_t)g * (K - kSplit) + (k - kSplit)];
        dst[(size_t)t * 8 + j] = f2b(f);
    }
}

__global__ __launch_bounds__(256) void k_cwp(
    const float* __restrict__ cw, unsigned short* __restrict__ dst)
{
    int t = blockIdx.x * 256 + threadIdx.x;
    if (t >= 512) return;
    int l = t & 63, r = t >> 6;
    int h = r * 16 + (l & 15);
    int kb = 8 * (l >> 4);
#pragma unroll
    for (int j = 0; j < 8; ++j) {
        int k = kb + j;
        dst[(size_t)t * 8 + j] = (k < KC) ? f2b(cw[h * KC + k]) : 0;
    }
}

__global__ __launch_bounds__(256) void k_cvt(
    const float* __restrict__ src, unsigned short* __restrict__ dst, int n)
{
    int i = blockIdx.x * 256 + threadIdx.x;
    if (i < n) dst[i] = f2b(src[i]);
}

// enc f32 [t][b][h] -> bf16 [b][t][h]
__global__ __launch_bounds__(256) void k_encb(
    const float* __restrict__ enc, unsigned short* __restrict__ out)
{
    int i = blockIdx.x * 256 + threadIdx.x;
    if (i >= Tt * Bb * HA) return;
    int h = i & 127, t = (i >> 7) & 255, b = i >> 15;
    out[i] = f2b(enc[((size_t)t * 32 + b) * 128 + h]);
}

__global__ __launch_bounds__(256) void k_fin(
    const float* __restrict__ tf, unsigned short* __restrict__ dst)
{
    int i = blockIdx.x * 256 + threadIdx.x;
    if (i >= Ff * Bb * Cc) return;
    int fb = i >> 7, cpos = i & 127;
    int f = fb >> 5, b = fb & 31;
    float v = (f == 0) ? -9.210340371976182f : tf[((size_t)(f - 1) * Bb + b) * Cc + cpos];
    dst[i] = f2b(v);
}

// ------------------------------------------------- prenet layer (MFMA) -----
__global__ __launch_bounds__(1024) void k_prelayer(
    const unsigned short* __restrict__ Wp, int nkc,
    const unsigned short* __restrict__ X, int rs,
    const float* __restrict__ bias, unsigned short* __restrict__ Y)
{
    int tid = threadIdx.x, l = tid & 63, w = tid >> 6;
    int lm = l & 15, lk = l >> 4;
    int fb0 = blockIdx.x * 16;
    f32x4 acc = {0.f, 0.f, 0.f, 0.f};
    const unsigned short* wp = Wp + (((size_t)w * nkc) << 9) + (l << 3);
    for (int kc = 0; kc < nkc; ++kc) {
        bf16x8 bb = *(const bf16x8*)(X + (size_t)(fb0 + lm) * rs + (kc << 5) + 8 * lk);
        bf16x8 aa = *(const bf16x8*)wp;
        acc = __builtin_amdgcn_mfma_f32_16x16x32_bf16(aa, bb, acc, 0, 0, 0);
        wp += 512;
    }
    short4v o;
#pragma unroll
    for (int rr = 0; rr < 4; ++rr) {
        float v = acc[rr] + bias[w * 16 + 4 * lk + rr];
        o[rr] = (short)f2b(fmaxf(v, 0.f));
    }
    *(short4v*)(Y + (size_t)(fb0 + lm) * 256 + w * 16 + 4 * lk) = o;
}

// ------------------------------------------------- split grid barrier ------
// arrive: drain this block's stores, post arrival flag. wait: block0
// aggregates + releases; others poll release. Work placed between arrive and
// wait executes in the barrier's shadow (its stores are ordered by the NEXT
// barrier's arrive).
__device__ __forceinline__ int poll_flag(int* p, int it) {
    if ((it & 63) == 63)
        return __hip_atomic_fetch_add(p, 0, __ATOMIC_RELAXED, __HIP_MEMORY_SCOPE_SYSTEM);
    return __hip_atomic_load(p, __ATOMIC_RELAXED, __HIP_MEMORY_SCOPE_SYSTEM);
}
__device__ __forceinline__ void bar_arrive(int* arr, int gen)
{
    __syncthreads();   // all waves drain stores (vmcnt 0) before flagging
    if (blockIdx.x != 0 && threadIdx.x == 0)
        __hip_atomic_store(&arr[blockIdx.x * FLAG_STRIDE], gen, __ATOMIC_RELAXED,
                           __HIP_MEMORY_SCOPE_SYSTEM);
}
__device__ __forceinline__ void bar_wait(int* arr, int* rel, int gen)
{
    if (blockIdx.x == 0) {
        int tid = threadIdx.x;
        if (tid >= 1 && tid < 256) {
            int cnt = 0;
            while (poll_flag(&arr[tid * FLAG_STRIDE], cnt) < gen) {
                __builtin_amdgcn_s_sleep(2);
                if (++cnt > 2000000) break;
            }
        }
        __syncthreads();
        if (tid < 8)
            __hip_atomic_store(&rel[tid * FLAG_STRIDE], gen, __ATOMIC_RELAXED,
                               __HIP_MEMORY_SCOPE_SYSTEM);
    } else {
        if (threadIdx.x == 0) {
            int cnt = 0;
            while (poll_flag(&rel[(blockIdx.x & 7) * FLAG_STRIDE], cnt) < gen) {
                __builtin_amdgcn_s_sleep(2);
                if (++cnt > 2000000) break;
            }
        }
    }
    __syncthreads();
}

// ------------------------------------------------- X fragment loaders ------
__device__ __forceinline__ bf16x8 xfrag1(
    int k, int f, int row,
    const unsigned short* p_bf, const unsigned short* ctx_bf,
    const unsigned short* spk_bf, const unsigned short* h1n)
{
    if (k < 256)  return *(const bf16x8*)(p_bf + ((size_t)(f * 32 + row)) * 256 + k);
    if (k < 384)  return *(const bf16x8*)(ctx_bf + ((size_t)(f * 32 + row)) * 128 + (k - 256));
    if (k < 512)  return *(const bf16x8*)(spk_bf + (size_t)row * 128 + (k - 384));
    return ldh8(h1n, f, k - 512, row);
}
__device__ __forceinline__ bf16x8 xfrag2(
    int k, int f, int row,
    const unsigned short* h1n, const unsigned short* ctx_bf,
    const unsigned short* spk_bf, const unsigned short* h2n)
{
    if (k < 1024) return ldh8(h1n, f, k, row);
    if (k < 1152) return *(const bf16x8*)(ctx_bf + ((size_t)(f * 32 + row)) * 128 + (k - 1024));
    if (k < 1280) return *(const bf16x8*)(spk_bf + (size_t)row * 128 + (k - 1152));
    return ldh8(h2n, f - 1, k - 1280, row);
}

// ------------------------------------------------- GEMM2 + cell2 (inline) --
// rt = row-tile (0..255) this call computes; runs on blocks 32..255 only.
__device__ __forceinline__ void gemm2cell(
    int f, int tid, int l, int w, int lm, int lk, int rt,
    const bf16x8 (&w2f)[9],
    const unsigned short* h1n, const unsigned short* ctx_bf,
    const unsigned short* spk_bf, unsigned short* h2n,
    const float* b2l, float* c2_s,
    f32x4 (*red)[2][64], float (*g_s)[4][16][4])
{
    f32x4 a0 = {0.f,0.f,0.f,0.f}, a1 = {0.f,0.f,0.f,0.f};
#pragma unroll
    for (int i = 0; i < 9; ++i) {
        int kk = (w * 9 + i) * 32 + 8 * lk;
        bf16x8 b0 = xfrag2(kk, f, lm, h1n, ctx_bf, spk_bf, h2n);
        bf16x8 b1 = xfrag2(kk, f, 16 + lm, h1n, ctx_bf, spk_bf, h2n);
        a0 = __builtin_amdgcn_mfma_f32_16x16x32_bf16(w2f[i], b0, a0, 0, 0, 0);
        a1 = __builtin_amdgcn_mfma_f32_16x16x32_bf16(w2f[i], b1, a1, 0, 0, 0);
    }
    __syncthreads();
    red[w][0][l] = a0; red[w][1][l] = a1;
    __syncthreads();
    if (tid < 128) {
        int ct = tid >> 6, ll = tid & 63;
        f32x4 s = red[0][ct][ll];
#pragma unroll
        for (int ww = 1; ww < 8; ++ww) s += red[ww][ct][ll];
        int llm = ll & 15, llk = ll >> 4;
#pragma unroll
        for (int rr = 0; rr < 4; ++rr) g_s[ct][llk][llm][rr] = s[rr];
    }
    __syncthreads();
    if (tid < 32) {
        int b = tid, ct = b >> 4, bl = b & 15;
        u64 pack = 0;
#pragma unroll
        for (int v = 0; v < 4; ++v) {
            int u = rt * 4 + v;
            float gi = g_s[ct][0][bl][v] + b2l[u];
            float gf = g_s[ct][1][bl][v] + b2l[1024 + u];
            float gg = g_s[ct][2][bl][v] + b2l[2048 + u];
            float go = g_s[ct][3][bl][v] + b2l[3072 + u];
            float cc = sigm(gf) * c2_s[b + 32 * v] + sigm(gi) * ftanh(gg);
            c2_s[b + 32 * v] = cc;
            pack |= (u64)f2b(sigm(go) * ftanh(cc)) << (16 * v);
        }
        st_sys_u64((u64*)(h2n + (size_t)f * 32768 + (size_t)rt * 128 + b * 4), pack);
    }
    __syncthreads();
}

// ------------------------------------------------- persistent decoder ------
// 256 blocks x 512 thr. All blocks: GEMM1 tile r. Blocks 32..255: GEMM2
// tile r-32 (blocks 32..63 also tile 224+(r-32)), run between bar1
// arrive/wait -> overlapped with attention on blocks 0..31.
__global__ __launch_bounds__(512) void k_persist(
    const unsigned short* __restrict__ W1p, const unsigned short* __restrict__ W2p,
    const unsigned short* __restrict__ p_bf, const unsigned short* __restrict__ spk_bf,
    unsigned short* __restrict__ h1n, unsigned short* __restrict__ h2n,
    unsigned short* __restrict__ ctx_bf,
    const float* __restrict__ b1l, const float* __restrict__ b2l,
    const unsigned short* __restrict__ encb, const unsigned short* __restrict__ wq_bf,
    const float* __restrict__ bq, const unsigned short* __restrict__ cwp,
    const float* __restrict__ cb, const float* __restrict__ av,
    float* __restrict__ align_f, int* __restrict__ bar_arr, int* __restrict__ bar_rel)
{
    const int tid = threadIdx.x;
    const int l = tid & 63, w = tid >> 6;
    const int lm = l & 15, lk = l >> 4;
    const int r = blockIdx.x;
    const bool isAttn = (r < 32);
    const int t1 = r - 32;
    const bool two = (r >= 32 && r < 64);
    const int t2 = 224 + (r - 32);

    bf16x8 w1f[6], w2fA[9], w2fB[9];
#pragma unroll
    for (int i = 0; i < 6; ++i)
        w1f[i] = *(const bf16x8*)(W1p + (((size_t)(r * 48 + w * 6 + i)) << 9) + (l << 3));
    if (!isAttn) {
#pragma unroll
        for (int i = 0; i < 9; ++i)
            w2fA[i] = *(const bf16x8*)(W2p + (((size_t)(t1 * 72 + w * 9 + i)) << 9) + (l << 3));
        if (two) {
#pragma unroll
            for (int i = 0; i < 9; ++i)
                w2fB[i] = *(const bf16x8*)(W2p + (((size_t)(t2 * 72 + w * 9 + i)) << 9) + (l << 3));
        }
    }

    __shared__ f32x4 red[8][2][64];
    __shared__ float g_s[2][4][16][4];
    __shared__ float c1_s[128], c2a_s[128], c2b_s[128];
    __shared__ float h1_sh[1024];
    __shared__ float qc_s[128];
    __shared__ float cum_s[292];
    __shared__ float e_s[256], a_s[256];
    __shared__ float ctx_p[4][128];
    __shared__ float redm[16];

    if (tid < 128) { c1_s[tid] = 0.f; c2a_s[tid] = 0.f; c2b_s[tid] = 0.f; }
    for (int i = tid; i < 292; i += 512) cum_s[i] = 0.f;
    __syncthreads();

    for (int f = 0; f < 128; ++f) {
        // ---------------- phase 1: GEMM1[f] + cell1 ----------------
        {
            f32x4 a0 = {0.f,0.f,0.f,0.f}, a1 = {0.f,0.f,0.f,0.f};
#pragma unroll
            for (int i = 0; i < 6; ++i) {
                int kk = (w * 6 + i) * 32 + 8 * lk;
                bf16x8 b0 = xfrag1(kk, f, lm, p_bf, ctx_bf, spk_bf, h1n);
                bf16x8 b1 = xfrag1(kk, f, 16 + lm, p_bf, ctx_bf, spk_bf, h1n);
                a0 = __builtin_amdgcn_mfma_f32_16x16x32_bf16(w1f[i], b0, a0, 0, 0, 0);
                a1 = __builtin_amdgcn_mfma_f32_16x16x32_bf16(w1f[i], b1, a1, 0, 0, 0);
            }
            red[w][0][l] = a0; red[w][1][l] = a1;
        }
        __syncthreads();
        if (tid < 128) {
            int ct = tid >> 6, ll = tid & 63;
            f32x4 s = red[0][ct][ll];
#pragma unroll
            for (int ww = 1; ww < 8; ++ww) s += red[ww][ct][ll];
            int llm = ll & 15, llk = ll >> 4;
#pragma unroll
            for (int rr = 0; rr < 4; ++rr) g_s[ct][llk][llm][rr] = s[rr];
        }
        __syncthreads();
        if (tid < 32) {
            int b = tid, ct = b >> 4, bl = b & 15;
            u64 pack = 0;
#pragma unroll
            for (int v = 0; v < 4; ++v) {
                int u = r * 4 + v;
                float gi = g_s[ct][0][bl][v] + b1l[u];
                float gf = g_s[ct][1][bl][v] + b1l[1024 + u];
                float gg = g_s[ct][2][bl][v] + b1l[2048 + u];
                float go = g_s[ct][3][bl][v] + b1l[3072 + u];
                float cc = sigm(gf) * c1_s[b + 32 * v] + sigm(gi) * ftanh(gg);
                c1_s[b + 32 * v] = cc;
                pack |= (u64)f2b(sigm(go) * ftanh(cc)) << (16 * v);
            }
            st_sys_u64((u64*)(h1n + (size_t)(f + 1) * 32768 + (size_t)r * 128 + b * 4), pack);
        }
        bar_arrive(bar_arr, 2 * f + 1);
        // GEMM2[f-1 semantics: uses slabs f,f-1] in barrier shadow (non-attn)
        if (!isAttn && f >= 1) {
            gemm2cell(f, tid, l, w, lm, lk, t1, w2fA, h1n, ctx_bf, spk_bf, h2n,
                      b2l, c2a_s, red, g_s);
            if (two)
                gemm2cell(f, tid, l, w, lm, lk, t2, w2fB, h1n, ctx_bf, spk_bf, h2n,
                          b2l, c2b_s, red, g_s);
        }
        bar_wait(bar_arr, bar_rel, 2 * f + 1);

        // ---------------- phase 2: attention (blocks 0..31) ----------------
        if (isAttn) {
            const int b = r;
            if (tid < 256) {
                u64 q = *(const u64*)(h1n + (size_t)(f + 1) * 32768 + (size_t)tid * 128 + b * 4);
#pragma unroll
                for (int j = 0; j < 4; ++j)
                    h1_sh[tid * 4 + j] = b2f((unsigned short)(q >> (16 * j)));
            }
            __syncthreads();
            // q = Wq.h1 + bq (+cb folded)
            {
                int o = tid >> 2, kq = tid & 3;
                const f32x4* hh = (const f32x4*)(h1_sh + kq * 256);
                const unsigned short* wr = wq_bf + (size_t)o * 1024 + kq * 256;
                float acc = 0.f;
#pragma unroll 4
                for (int i2 = 0; i2 < 32; ++i2) {
                    bf16x8 wv = *(const bf16x8*)(wr + i2 * 8);
                    f32x4 x0 = hh[i2 * 2], x1 = hh[i2 * 2 + 1];
                    acc += b2f((unsigned short)wv[0]) * x0[0] + b2f((unsigned short)wv[1]) * x0[1]
                         + b2f((unsigned short)wv[2]) * x0[2] + b2f((unsigned short)wv[3]) * x0[3]
                         + b2f((unsigned short)wv[4]) * x1[0] + b2f((unsigned short)wv[5]) * x1[1]
                         + b2f((unsigned short)wv[6]) * x1[2] + b2f((unsigned short)wv[7]) * x1[3];
                }
                acc += __shfl_xor(acc, 1); acc += __shfl_xor(acc, 2);
                if (kq == 0) qc_s[o] = acc + bq[o] + cb[o];
            }
            __syncthreads();
#pragma unroll
            for (int p = 0; p < 2; ++p) {
                int t0 = (w + 8 * p) * 16;
                bf16x8 bfr;
#pragma unroll
                for (int j = 0; j < 8; ++j) bfr[j] = (short)f2b(cum_s[t0 + lm + 8 * lk + j]);
                float e = 0.f;
                int t = t0 + lm;
#pragma unroll
                for (int m = 0; m < 8; ++m) {
                    bf16x8 afr = *(const bf16x8*)(cwp + (((size_t)(m * 64 + l)) << 3));
                    f32x4 acc = {0.f,0.f,0.f,0.f};
                    acc = __builtin_amdgcn_mfma_f32_16x16x32_bf16(afr, bfr, acc, 0, 0, 0);
                    const unsigned short* ep = encb + ((size_t)b << 15) + (size_t)t * 128 + m * 16 + 4 * lk;
                    short4v ev4 = *(const short4v*)ep;
#pragma unroll
                    for (int rr = 0; rr < 4; ++rr) {
                        int h = m * 16 + 4 * lk + rr;
                        e += ftanh(qc_s[h] + b2f((unsigned short)ev4[rr]) + acc[rr]) * av[h];
                    }
                }
                e += __shfl_xor(e, 16); e += __shfl_xor(e, 32);
                if (l < 16) e_s[t0 + l] = e;
            }
            __syncthreads();
            if (tid < 256) {
                float e = e_s[tid], mm = e;
#pragma unroll
                for (int off = 1; off < 64; off <<= 1) mm = fmaxf(mm, __shfl_xor(mm, off));
                if ((tid & 63) == 0) redm[tid >> 6] = mm;
            }
            __syncthreads();
            if (tid < 256) {
                float mm = fmaxf(fmaxf(redm[0], redm[1]), fmaxf(redm[2], redm[3]));
                float ex = __expf(e_s[tid] - mm);
                a_s[tid] = ex;
                float s = ex;
#pragma unroll
                for (int off = 1; off < 64; off <<= 1) s += __shfl_xor(s, off);
                if ((tid & 63) == 0) redm[8 + (tid >> 6)] = s;
            }
            __syncthreads();
            if (tid < 256) {
                float s = redm[8] + redm[9] + redm[10] + redm[11];
                float a = __fdividef(a_s[tid], s);
                a_s[tid] = a;
                cum_s[15 + tid] += a;
                align_f[((size_t)f * 32 + b) * 256 + tid] = a;
            }
            __syncthreads();
            {
                int h = tid & 127, tq = tid >> 7;
                float acc = 0.f;
                const unsigned short* ep = encb + ((size_t)b << 15) + (size_t)(tq * 64) * 128 + h;
#pragma unroll 4
                for (int t2i = 0; t2i < 64; ++t2i)
                    acc += a_s[tq * 64 + t2i] * b2f(ep[(size_t)t2i * 128]);
                ctx_p[tq][h] = acc;
            }
            __syncthreads();
            if (tid < 32) {
                u64 pack = 0;
#pragma unroll
                for (int j = 0; j < 4; ++j) {
                    int h = tid * 4 + j;
                    float s2 = ctx_p[0][h] + ctx_p[1][h] + ctx_p[2][h] + ctx_p[3][h];
                    pack |= (u64)f2b(s2) << (16 * j);
                }
                st_sys_u64((u64*)(ctx_bf + ((size_t)(f + 1) * 32 + b) * 128 + tid * 4), pack);
            }
        }
        bar_arrive(bar_arr, 2 * f + 2);
        bar_wait(bar_arr, bar_rel, 2 * f + 2);
    }
    // tail: GEMM2+cell2 for step 127 (slabs 128/127)
    if (!isAttn) {
        gemm2cell(128, tid, l, w, lm, lk, t1, w2fA, h1n, ctx_bf, spk_bf, h2n,
                  b2l, c2a_s, red, g_s);
        if (two)
            gemm2cell(128, tid, l, w, lm, lk, t2, w2fB, h1n, ctx_bf, spk_bf, h2n,
                      b2l, c2b_s, red, g_s);
    }
}

// ------------------------------------------------- final projection --------
__global__ __launch_bounds__(512) void k_outproj(
    const unsigned short* __restrict__ Wp,
    const unsigned short* __restrict__ h2n, const unsigned short* __restrict__ ctxb,
    const unsigned short* __restrict__ spkb,
    const float* __restrict__ ob, float* __restrict__ frames)
{
    int tid = threadIdx.x, l = tid & 63, w = tid >> 6;
    int lm = l & 15, lk = l >> 4;
    int fb0 = blockIdx.x * 16;
    int fb = fb0 + lm, fslab = (fb >> 5) + 1, b = fb & 31;
    f32x4 acc = {0.f, 0.f, 0.f, 0.f};
    const unsigned short* wp = Wp + (((size_t)w * 40) << 9) + (l << 3);
    for (int kc = 0; kc < 40; ++kc) {
        int kg = kc << 5;
        bf16x8 bb;
        if (kg < 1024)
            bb = ldh8(h2n, fslab, kg + 8 * lk, b);
        else if (kg < 1152)
            bb = *(const bf16x8*)(ctxb + ((size_t)fslab * 32 + b) * 128 + (kg - 1024) + 8 * lk);
        else
            bb = *(const bf16x8*)(spkb + (size_t)b * 128 + (kg - 1152) + 8 * lk);
        bf16x8 aa = *(const bf16x8*)wp;
        acc = __builtin_amdgcn_mfma_f32_16x16x32_bf16(aa, bb, acc, 0, 0, 0);
        wp += 512;
    }
    f32x4 ov = *(const f32x4*)(ob + w * 16 + 4 * lk);
    *(f32x4*)(frames + (size_t)fb * 128 + w * 16 + 4 * lk) = acc + ov;
}

// ------------------------------------------------- stop projection ---------
__global__ __launch_bounds__(256) void k_stop(
    const unsigned short* __restrict__ h2n, const unsigned short* __restrict__ spkb,
    const unsigned short* __restrict__ swb, const float* __restrict__ sb,
    float* __restrict__ stop)
{
    int tid = threadIdx.x;
    int fb = blockIdx.x * 32 + (tid >> 3);
    int fslab = (fb >> 5) + 1, b = fb & 31;
    int kb = (tid & 7) * 8;
    float acc = 0.f;
    for (int i = 0; i < 18; ++i) {
        int k = kb + 64 * i;
        bf16x8 xv;
        if (k < 1024) xv = ldh8(h2n, fslab, k, b);
        else          xv = *(const bf16x8*)(spkb + (size_t)b * 128 + (k - 1024));
        bf16x8 wv = *(const bf16x8*)(swb + k);
#pragma unroll
        for (int j = 0; j < 8; ++j)
            acc += b2f((unsigned short)xv[j]) * b2f((unsigned short)wv[j]);
    }
    acc += __shfl_xor(acc, 1); acc += __shfl_xor(acc, 2); acc += __shfl_xor(acc, 4);
    if ((tid & 7) == 0) stop[fb] = acc + sb[0];
}

// ------------------------------------------------------------------ host ----
extern "C" void kernel_launch(void* const* d_in, const int* in_sizes, int n_in,
                              void* d_out, int out_size, void* d_ws, size_t ws_size,
                              hipStream_t stream)
{
    const float* enc  = (const float*)d_in[0];
    const float* spk  = (const float*)d_in[2];
    const float* tf   = (const float*)d_in[3];
    const float* pw1  = (const float*)d_in[4];
    const float* pb1  = (const float*)d_in[5];
    const float* pw2  = (const float*)d_in[6];
    const float* pb2  = (const float*)d_in[7];
    const float* w1ih = (const float*)d_in[8];
    const float* w1hh = (const float*)d_in[9];
    const float* b1l  = (const float*)d_in[10];
    const float* w2ih = (const float*)d_in[11];
    const float* w2hh = (const float*)d_in[12];
    const float* b2l  = (const float*)d_in[13];
    const float* cw   = (const float*)d_in[14];
    const float* cb   = (const float*)d_in[15];
    const float* wq   = (const float*)d_in[16];
    const float* bq   = (const float*)d_in[17];
    const float* av   = (const float*)d_in[18];
    const float* ow   = (const float*)d_in[19];
    const float* ob   = (const float*)d_in[20];
    const float* sw   = (const float*)d_in[21];
    const float* sb   = (const float*)d_in[22];

    char* base = (char*)d_ws;
    size_t off = 0;
    auto take = [&](size_t bytes) {
        char* p = base + off;
        off += (bytes + 255) & ~(size_t)255;
        return p;
    };
    unsigned short* W1p    = (unsigned short*)take(4096u * 1536 * 2);
    unsigned short* W2p    = (unsigned short*)take(4096u * 2304 * 2);
    unsigned short* outWp  = (unsigned short*)take(128u * 1280 * 2);
    unsigned short* pw1p   = (unsigned short*)take(256u * 128 * 2);
    unsigned short* pw2p   = (unsigned short*)take(256u * 256 * 2);
    unsigned short* cwp    = (unsigned short*)take(512u * 8 * 2);
    unsigned short* wq_bf  = (unsigned short*)take(128u * 1024 * 2);
    unsigned short* sw_bf  = (unsigned short*)take(1152u * 2);
    unsigned short* spk_bf = (unsigned short*)take(32u * 128 * 2);
    unsigned short* enc_bf = (unsigned short*)take((size_t)Bb * Tt * HA * 2);
    unsigned short* fin_bf = (unsigned short*)take(4096u * 128 * 2);
    unsigned short* P1_bf  = (unsigned short*)take(4096u * 256 * 2);
    unsigned short* p_bf   = (unsigned short*)take(4096u * 256 * 2);
    unsigned short* h1n    = (unsigned short*)take(129u * 32768 * 2);
    unsigned short* h2n    = (unsigned short*)take(129u * 32768 * 2);
    unsigned short* ctx_bfs= (unsigned short*)take(129u * 32 * 128 * 2);
    int* bar = (int*)take((256 * FLAG_STRIDE + 8 * FLAG_STRIDE) * 4);
    int* bar_arr = bar;
    int* bar_rel = bar + 256 * FLAG_STRIDE;

    float* frames_out = (float*)d_out;                       // [F][B][128]
    float* stop_out   = frames_out + (size_t)Ff * Bb * Cc;   // [F][B]
    float* align_out  = stop_out + Ff * Bb;                  // [F][B][256]

    // ---- prologue: weight repacks + converts + state init ----
    k_repack<<<dim3(3072), dim3(256), 0, stream>>>(w1ih, w1hh, 512, 1536, 256 * 48 * 64, 1, W1p);
    k_repack<<<dim3(4608), dim3(256), 0, stream>>>(w2ih, w2hh, 1280, 2304, 256 * 72 * 64, 1, W2p);
    k_repack<<<dim3((8 * 40 * 64 + 255) / 256), dim3(256), 0, stream>>>(ow, ow, 1280, 1280, 8 * 40 * 64, 0, outWp);
    k_repack<<<dim3((16 * 4 * 64 + 255) / 256), dim3(256), 0, stream>>>(pw1, pw1, 128, 128, 16 * 4 * 64, 0, pw1p);
    k_repack<<<dim3((16 * 8 * 64 + 255) / 256), dim3(256), 0, stream>>>(pw2, pw2, 256, 256, 16 * 8 * 64, 0, pw2p);
    k_cwp<<<dim3(2), dim3(256), 0, stream>>>(cw, cwp);
    k_cvt<<<dim3(16), dim3(256), 0, stream>>>(spk, spk_bf, 4096);
    k_cvt<<<dim3(512), dim3(256), 0, stream>>>(wq, wq_bf, 131072);
    k_cvt<<<dim3(5), dim3(256), 0, stream>>>(sw, sw_bf, 1152);
    k_encb<<<dim3(4096), dim3(256), 0, stream>>>(enc, enc_bf);
    k_fin<<<dim3(2048), dim3(256), 0, stream>>>(tf, fin_bf);

    hipMemsetAsync(bar, 0, (256 * FLAG_STRIDE + 8 * FLAG_STRIDE) * 4, stream);
    hipMemsetAsync(h1n, 0, 32768u * 2, stream);          // h1 state slab 0 = 0
    hipMemsetAsync(h2n, 0, 32768u * 2, stream);          // h2 state slab 0 = 0
    hipMemsetAsync(ctx_bfs, 0, 32u * 128 * 2, stream);   // ctx slab 0 = 0

    // prenet (both layers, all frames)
    k_prelayer<<<dim3(256), dim3(1024), 0, stream>>>(pw1p, 4, fin_bf, 128, pb1, P1_bf);
    k_prelayer<<<dim3(256), dim3(1024), 0, stream>>>(pw2p, 8, P1_bf, 256, pb2, p_bf);

    // ---- persistent decode (both LSTMs + attention, all 128 steps) ----
    k_persist<<<dim3(256), dim3(512), 0, stream>>>(
        W1p, W2p, p_bf, spk_bf, h1n, h2n, ctx_bfs,
        b1l, b2l, enc_bf, wq_bf, bq, cwp, cb, av,
        align_out, bar_arr, bar_rel);

    // ---- epilogue ----
    k_outproj<<<dim3(256), dim3(512), 0, stream>>>(
        outWp, h2n, ctx_bfs, spk_bf, ob, frames_out);
    k_stop<<<dim3(128), dim3(256), 0, stream>>>(
        h2n, spk_bf, sw_bf, sb, stop_out);
}